// Round 1
// baseline (330.123 us; speedup 1.0000x reference)
//
#include <hip/hip_runtime.h>

// CutOut: images (64,512,512,3) fp32, labels (64,) i32, center_h (64,) i32,
// center_w (64,) i32. Output = [masked images (50,331,648 f32)] ++ [labels (64)].
// FILL_VALUE = 0, LENGTH = 50 (HALF = 25).
//
// Plan: D2D memcpy for the bulk (copy engine ~85% HBM peak), then a tiny
// kernel that zeroes only the clipped cutout boxes (<=1% of pixels) and
// writes the labels tail as float.

#define HALF   25
#define BATCH  64
#define IMG_H  512
#define IMG_W  512
#define IMG_C  3
#define IMG_ELEMS ((size_t)BATCH * IMG_H * IMG_W * IMG_C)

__global__ void cutout_zero_and_labels(float* __restrict__ out,
                                       const int* __restrict__ center_h,
                                       const int* __restrict__ center_w,
                                       const int* __restrict__ labels,
                                       float* __restrict__ out_labels) {
    const int b = blockIdx.y;

    // Block (0,0) also emits the labels tail (64 floats).
    if (blockIdx.x == 0 && blockIdx.y == 0 && threadIdx.x < BATCH) {
        out_labels[threadIdx.x] = (float)labels[threadIdx.x];
    }

    const int r = center_h[b] - HALF + (int)blockIdx.x;   // blockIdx.x in [0, 50)
    if (r < 0 || r >= IMG_H) return;

    const int cw = center_w[b];
    const int c0 = max(0, cw - HALF);
    const int c1 = min(IMG_W, cw + HALF);
    const int n  = (c1 - c0) * IMG_C;                     // <= 150 floats
    if (n <= 0) return;

    const size_t base = (((size_t)b * IMG_H + r) * IMG_W + c0) * IMG_C;
    for (int i = threadIdx.x; i < n; i += blockDim.x) {
        out[base + i] = 0.0f;
    }
}

extern "C" void kernel_launch(void* const* d_in, const int* in_sizes, int n_in,
                              void* d_out, int out_size, void* d_ws, size_t ws_size,
                              hipStream_t stream) {
    const float* images   = (const float*)d_in[0];
    const int*   labels   = (const int*)  d_in[1];
    const int*   center_h = (const int*)  d_in[2];
    const int*   center_w = (const int*)  d_in[3];
    float* out = (float*)d_out;

    // Bulk copy of all image data (cutout region overwritten below).
    hipMemcpyAsync(out, images, IMG_ELEMS * sizeof(float),
                   hipMemcpyDeviceToDevice, stream);

    // Zero the boxes + write labels. Grid: 50 candidate rows x 64 batches.
    dim3 grid(2 * HALF, BATCH);
    cutout_zero_and_labels<<<grid, 192, 0, stream>>>(
        out, center_h, center_w, labels, out + IMG_ELEMS);
}

// Round 2
// 321.417 us; speedup vs baseline: 1.0271x; 1.0271x over previous
//
#include <hip/hip_runtime.h>

// CutOut fused copy+mask: images (64,512,512,3) f32 -> out, zeroing a
// 50x50 box (clipped) per batch centered at (center_h[b], center_w[b]).
// Output tail: labels (64) as f32.
//
// Memory-bound: 201 MB read + 201 MB write. One float4 per thread.
// 4 consecutive floats span at most 2 pixels (C=3): two box tests,
// per-element select. H=W=512 are pow2 -> shifts; /3 is a magic-mul.

#define HALF   25
#define BATCH  64
#define IMG_H  512
#define IMG_W  512
#define IMG_C  3
#define N_PIX  (BATCH * IMG_H * IMG_W)            // 16,777,216
#define N_ELEM ((size_t)N_PIX * IMG_C)            // 50,331,648
#define N_VEC  (N_ELEM / 4)                       // 12,582,912 float4s

__device__ __forceinline__ bool inbox(unsigned p,
                                      const int* __restrict__ ch,
                                      const int* __restrict__ cw) {
    const int w = (int)(p & (IMG_W - 1));
    const int h = (int)((p >> 9) & (IMG_H - 1));
    const int b = (int)(p >> 18);
    const int chb = ch[b];      // wave-uniform -> L1 broadcast
    const int cwb = cw[b];
    return (h >= chb - HALF) & (h < chb + HALF) &
           (w >= cwb - HALF) & (w < cwb + HALF);
}

__global__ __launch_bounds__(256) void cutout_fused(
    const float4* __restrict__ in,
    float4* __restrict__ out,
    const int* __restrict__ center_h,
    const int* __restrict__ center_w,
    const int* __restrict__ labels,
    float* __restrict__ out_labels)
{
    const unsigned vid = blockIdx.x * 256u + threadIdx.x;   // < N_VEC < 2^24

    if (blockIdx.x == 0 && threadIdx.x < BATCH) {
        out_labels[threadIdx.x] = (float)labels[threadIdx.x];
    }

    float4 v = in[vid];

    const unsigned idx4 = vid * 4u;              // element base, < 2^26
    const unsigned pi   = idx4 / 3u;             // pixel of element 0 (magic-mul)
    const unsigned rem  = idx4 - pi * 3u;        // channel of element 0

    // Elements 0..3 live in pixel pi or pi+1:
    //   e0 -> pi;  e1 -> (rem>=2 ? pi+1 : pi);  e2 -> (rem>=1 ? pi+1 : pi);  e3 -> pi+1
    const bool m0 = inbox(pi,     center_h, center_w);
    const bool m1 = inbox(pi + 1, center_h, center_w);  // pi+1 <= N_PIX-1 always

    const bool me0 = m0;
    const bool me1 = (rem >= 2) ? m1 : m0;
    const bool me2 = (rem >= 1) ? m1 : m0;
    const bool me3 = m1;

    if (me0) v.x = 0.0f;
    if (me1) v.y = 0.0f;
    if (me2) v.z = 0.0f;
    if (me3) v.w = 0.0f;

    out[vid] = v;
}

extern "C" void kernel_launch(void* const* d_in, const int* in_sizes, int n_in,
                              void* d_out, int out_size, void* d_ws, size_t ws_size,
                              hipStream_t stream) {
    const float* images   = (const float*)d_in[0];
    const int*   labels   = (const int*)  d_in[1];
    const int*   center_h = (const int*)  d_in[2];
    const int*   center_w = (const int*)  d_in[3];
    float* out = (float*)d_out;

    const unsigned nblocks = N_VEC / 256;        // 49152, exact
    cutout_fused<<<nblocks, 256, 0, stream>>>(
        (const float4*)images, (float4*)out,
        center_h, center_w, labels, out + N_ELEM);
}